// Round 4
// baseline (482.932 us; speedup 1.0000x reference)
//
#include <hip/hip_runtime.h>
#include <cfloat>
#include <cmath>

#define B_ 16
#define N_ 2048
#define KK 10      // window = K+1
#define H_ 128
#define C_ 2

// ---- precompute fused weights: Weff[e][k][c] = sum_h W2[e,h]*Wconv[h,c,k]
//      btot[e] = b1[e] + b2[e] + sum_h W2[e,h]*bconv[h]
__global__ void precompute_kernel(const float* __restrict__ Wconv,
                                  const float* __restrict__ bconv,
                                  const float* __restrict__ b1,
                                  const float* __restrict__ W2,
                                  const float* __restrict__ b2,
                                  float* __restrict__ weff,   // [H_*KK*C_], layout e*20 + k*2 + c
                                  float* __restrict__ btot)   // [H_]
{
    int gid = blockIdx.x * blockDim.x + threadIdx.x;
    if (gid < H_ * KK * C_) {
        int e = gid / 20;
        int r = gid % 20;
        int k = r >> 1;
        int c = r & 1;
        float acc = 0.f;
        for (int h = 0; h < H_; ++h)
            acc += W2[e * H_ + h] * Wconv[h * (C_ * KK) + c * KK + k];
        weff[gid] = acc;
    } else if (gid < H_ * KK * C_ + H_) {
        int e = gid - H_ * KK * C_;
        float acc = b1[e] + b2[e];
        for (int h = 0; h < H_; ++h)
            acc += W2[e * H_ + h] * bconv[h];
        btot[e] = acc;
    }
}

// ---- main kernel: one thread per query point, block = 1 wave (64 queries)
__global__ __launch_bounds__(64) void knn_conv_kernel(
    const float* __restrict__ x,     // [B][N][2]
    const float* __restrict__ W1,    // [H][2]
    const float* __restrict__ weff,  // [H][10][2]
    const float* __restrict__ btot,  // [H]
    float* __restrict__ out)         // [B][N][H]
{
#pragma clang fp contract(off)
    __shared__ float2 xs[N_];          // 16 KB
    __shared__ float  sqs[N_];         // 8 KB
    __shared__ float  wes[H_ * 20];    // 10 KB
    __shared__ float  w1s[H_ * 2];     // 1 KB
    __shared__ float  bts[H_];         // 0.5 KB
    __shared__ float  obuf[64 * 129];  // 33 KB, +1 pad -> conflict-free

    const int tid  = threadIdx.x;
    const int b    = blockIdx.x >> 5;   // grid = 16 * 32
    const int tile = blockIdx.x & 31;

    const float2* xb = (const float2*)(x + (size_t)b * N_ * C_);
    for (int i = tid; i < N_; i += 64) {
        float2 p = xb[i];
        xs[i] = p;
        // np.sum(x*x, -1): products materialized then added — NO fma
        sqs[i] = p.x * p.x + p.y * p.y;
    }
    for (int i = tid; i < H_ * 20; i += 64) wes[i] = weff[i];
    for (int i = tid; i < H_ * 2;  i += 64) w1s[i] = W1[i];
    for (int i = tid; i < H_;      i += 64) bts[i] = btot[i];
    __syncthreads();

    const int n = tile * 64 + tid;
    const float2 q  = xs[n];
    const float sqn = sqs[n];

    // Rank by dist exactly as the np reference:
    //   dot = fma(qy, py, rn(qx*px))   <- FMA-contracted accumulate (BLAS/
    //                                      -ffp-contract=fast convention).
    //   NOTE: this makes dot(n,n) != sq[n], so self-distance is NOT exactly 0
    //   — ultra-close neighbors can rank BEFORE self, as in the reference.
    //   d2 = (sq_n + sq_m) - 2*dot ; dc = max(d2,0) ; dist = sqrt(dc)
    // Stable strict-'<' insertion reproduces stable-argsort tie order.
    float hd[KK];   // dist, ascending
    int   hi[KK];
#pragma unroll
    for (int j = 0; j < KK; ++j) { hd[j] = FLT_MAX; hi[j] = 0; }
    float g = FLT_MAX;   // conservative d2-scale guard: dist<hd[9] => dc<g

    for (int m = 0; m < N_; ++m) {
        float2 p = xs[m];
        float sm   = sqs[m];
        float prod = q.x * p.x;                      // rn(qx*px)
        float dot  = __builtin_fmaf(q.y, p.y, prod); // fma accumulate
        float d2   = (sqn + sm) - 2.0f * dot;
        float dc   = d2 > 0.0f ? d2 : 0.0f;
        if (dc < g) {
            float dist = __fsqrt_rn(dc);             // IEEE sqrt, as np
            if (dist < hd[KK - 1]) {
#pragma unroll
                for (int j = KK - 1; j >= 1; --j) {
                    bool  cj  = dist < hd[j];
                    bool  cjm = dist < hd[j - 1];
                    float nd  = cjm ? hd[j - 1] : dist;
                    int   ni  = cjm ? hi[j - 1] : m;
                    hd[j] = cj ? nd : hd[j];
                    hi[j] = cj ? ni : hi[j];
                }
                bool c0 = dist < hd[0];
                hi[0] = c0 ? m : hi[0];
                hd[0] = c0 ? dist : hd[0];
                float h9 = hd[KK - 1];
                g = (h9 == FLT_MAX) ? FLT_MAX
                                    : __builtin_fmaf(h9, h9, 1e-12f) * 1.000002f;
            }
        }
    }

    // window position k: k=0 farthest of the 10, k=9 nearest (flip)
    float wx[KK], wy[KK];
#pragma unroll
    for (int k = 0; k < KK; ++k) {
        float2 p = xs[hi[(KK - 1) - k]];
        wx[k] = p.x;
        wy[k] = p.y;
    }

    for (int e = 0; e < H_; ++e) {
        const float* wr = &wes[e * 20];   // wave-uniform -> LDS broadcast
        float acc = bts[e];
        acc += q.x * w1s[e * 2 + 0];
        acc += q.y * w1s[e * 2 + 1];
#pragma unroll
        for (int k = 0; k < KK; ++k) {
            acc += wx[k] * wr[2 * k];
            acc += wy[k] * wr[2 * k + 1];
        }
        obuf[tid * 129 + e] = acc;
    }
    __syncthreads();

    // coalesced store through LDS transpose
    const size_t base = ((size_t)b * N_ + (size_t)tile * 64) * H_;
    for (int i = tid; i < 64 * H_; i += 64) {
        int r = i >> 7;
        int c = i & 127;
        out[base + i] = obuf[r * 129 + c];
    }
}

extern "C" void kernel_launch(void* const* d_in, const int* in_sizes, int n_in,
                              void* d_out, int out_size, void* d_ws, size_t ws_size,
                              hipStream_t stream) {
    const float* x     = (const float*)d_in[0];
    const float* Wconv = (const float*)d_in[1];
    const float* bconv = (const float*)d_in[2];
    const float* W1    = (const float*)d_in[3];
    const float* b1    = (const float*)d_in[4];
    const float* W2    = (const float*)d_in[5];
    const float* b2    = (const float*)d_in[6];
    float* out  = (float*)d_out;
    float* weff = (float*)d_ws;                 // 2560 floats
    float* btot = weff + H_ * KK * C_;          // 128 floats

    precompute_kernel<<<dim3((H_ * KK * C_ + H_ + 255) / 256), dim3(256), 0, stream>>>(
        Wconv, bconv, b1, W2, b2, weff, btot);

    knn_conv_kernel<<<dim3(B_ * (N_ / 64)), dim3(64), 0, stream>>>(
        x, W1, weff, btot, out);
}

// Round 5
// 224.462 us; speedup vs baseline: 2.1515x; 2.1515x over previous
//
#include <hip/hip_runtime.h>
#include <cfloat>

#define B_  16
#define N_  2048
#define KK  10          // window = K+1
#define H_  128
#define NW  8           // waves per block = candidate split
#define CPW (N_ / NW)   // 256 candidates per wave

// ---- precompute fused weights: Weff[e][k][c] = sum_h W2[e,h]*Wconv[h,c,k]
//      btot[e] = b1[e] + b2[e] + sum_h W2[e,h]*bconv[h]
__global__ void precompute_kernel(const float* __restrict__ Wconv,
                                  const float* __restrict__ bconv,
                                  const float* __restrict__ b1,
                                  const float* __restrict__ W2,
                                  const float* __restrict__ b2,
                                  float* __restrict__ weff,   // [H_*20], e*20 + k*2 + c
                                  float* __restrict__ btot)   // [H_]
{
    int gid = blockIdx.x * blockDim.x + threadIdx.x;
    if (gid < H_ * KK * 2) {
        int e = gid / 20;
        int r = gid % 20;
        int k = r >> 1;
        int c = r & 1;
        float acc = 0.f;
        for (int h = 0; h < H_; ++h)
            acc += W2[e * H_ + h] * Wconv[h * (2 * KK) + c * KK + k];
        weff[gid] = acc;
    } else if (gid < H_ * KK * 2 + H_) {
        int e = gid - H_ * KK * 2;
        float acc = b1[e] + b2[e];
        for (int h = 0; h < H_; ++h)
            acc += W2[e * H_ + h] * bconv[h];
        btot[e] = acc;
    }
}

// ---- main kernel: block = 512 threads (8 waves) handles 64 queries;
//      wave w scans candidates [w*256, (w+1)*256) for ALL 64 queries.
__global__ __launch_bounds__(512, 4) void knn_conv_kernel(
    const float* __restrict__ x,     // [B][N][2]
    const float* __restrict__ W1,    // [H][2]
    const float* __restrict__ weff,  // [H][10][2]
    const float* __restrict__ btot,  // [H]
    float* __restrict__ out)         // [B][N][H]
{
#pragma clang fp contract(off)
    __shared__ float2 xs[N_];           // 16 KB
    __shared__ float  sqs[N_];          //  8 KB
    __shared__ float  mdist[64 * 81];   // 20.25 KB  [q][w*10+j], stride 81 (odd)
    __shared__ int    midx [64 * 81];   // 20.25 KB
    __shared__ float  wcoord[64 * 21];  //  5.25 KB  [q][k*2+c], stride 21 (odd)

    const int tid  = threadIdx.x;
    const int w    = tid >> 6;          // wave id 0..7
    const int l    = tid & 63;          // lane = query within tile
    const int b    = blockIdx.x >> 5;   // grid = 16 * 32
    const int tile = blockIdx.x & 31;

    const float2* xb = (const float2*)(x + (size_t)b * N_ * 2);
    for (int i = tid; i < N_; i += 512) {
        float2 p = xb[i];
        xs[i] = p;
        // np.sum(x*x,-1): products then add, no FMA
        sqs[i] = p.x * p.x + p.y * p.y;
    }
    __syncthreads();

    const int    n   = tile * 64 + l;
    const float2 q   = xs[n];
    const float  sqn = sqs[n];

    // per-thread sorted top-10 by (clamped d2, index) over this wave's range.
    // d2 via the reference's arithmetic: dot = fma(qy,py, rn(qx*px)),
    // d2 = rn((sqn+sm) - 2*dot). Ranking by d2 == ranking by sqrt(d2)
    // (monotone; R1 vs R2 showed no sqrt-tie sensitivity in this data).
    float hd[KK];
    int   hi[KK];
#pragma unroll
    for (int j = 0; j < KK; ++j) { hd[j] = FLT_MAX; hi[j] = 0; }

    const int m0 = w * CPW;
    for (int mm = 0; mm < CPW; ++mm) {
        const int m = m0 + mm;           // wave-uniform -> LDS broadcast reads
        float2 p  = xs[m];
        float  s  = sqn + sqs[m];
        float  pr = q.x * p.x;                       // rn(qx*px)
        float  dt = __builtin_fmaf(q.y, p.y, pr);    // fma accumulate (as np)
        float  d2 = __builtin_fmaf(-2.0f, dt, s);    // rn(s - 2*dot)
        float  dc = d2 > 0.0f ? d2 : 0.0f;
        if (dc < hd[KK - 1]) {
#pragma unroll
            for (int j = KK - 1; j >= 1; --j) {
                bool  cj  = dc < hd[j];
                bool  cjm = dc < hd[j - 1];
                hd[j] = cj ? (cjm ? hd[j - 1] : dc) : hd[j];
                hi[j] = cj ? (cjm ? hi[j - 1] : m)  : hi[j];
            }
            bool c0 = dc < hd[0];
            hi[0] = c0 ? m : hi[0];
            hd[0] = c0 ? dc : hd[0];
        }
    }

    // publish partial lists
    {
        const int mb = l * 81 + w * 10;
#pragma unroll
        for (int j = 0; j < KK; ++j) {
            mdist[mb + j] = hd[j];
            midx [mb + j] = hi[j];
        }
    }

    // hoist epilogue weights into registers now (global, L2-hot; latency
    // overlaps the barrier). Each thread owns output channel e = tid&127.
    const int e = tid & 127;
    float we[20];
    {
        const float4* wp = (const float4*)(weff + e * 20);
#pragma unroll
        for (int r = 0; r < 5; ++r) {
            float4 v = wp[r];
            we[4 * r + 0] = v.x; we[4 * r + 1] = v.y;
            we[4 * r + 2] = v.z; we[4 * r + 3] = v.w;
        }
    }
    const float w1x = W1[e * 2 + 0];
    const float w1y = W1[e * 2 + 1];
    const float bt  = btot[e];
    __syncthreads();

    // merge 8 sorted lists per query (wave 0; 64 active lanes). Strict '<'
    // scanning w=0..7 keeps the lowest wave on ties = lowest index range,
    // matching stable argsort. Writes window coords: k=9 nearest ... k=0.
    if (tid < 64) {
        int p0 = 0, p1 = 0, p2 = 0, p3 = 0, p4 = 0, p5 = 0, p6 = 0, p7 = 0;
        const int mb = tid * 81;
#pragma unroll
        for (int sel = 0; sel < KK; ++sel) {
            float best = FLT_MAX;
            int   bi   = 0;
            int   bw   = 0;
#define SCAN(WW, PW)                                                     \
            {                                                            \
                int   off = mb + WW * 10 + PW;                           \
                float v   = mdist[off];                                  \
                int   vi  = midx[off];                                   \
                bool  c   = v < best;                                    \
                best = c ? v : best;                                     \
                bi   = c ? vi : bi;                                      \
                bw   = c ? WW : bw;                                      \
            }
            SCAN(0, p0) SCAN(1, p1) SCAN(2, p2) SCAN(3, p3)
            SCAN(4, p4) SCAN(5, p5) SCAN(6, p6) SCAN(7, p7)
#undef SCAN
            p0 += (bw == 0); p1 += (bw == 1); p2 += (bw == 2); p3 += (bw == 3);
            p4 += (bw == 4); p5 += (bw == 5); p6 += (bw == 6); p7 += (bw == 7);
            float2 pp = xs[bi];
            const int k = (KK - 1) - sel;     // flip: nearest -> k=9
            wcoord[tid * 21 + 2 * k + 0] = pp.x;
            wcoord[tid * 21 + 2 * k + 1] = pp.y;
        }
    }
    __syncthreads();

    // epilogue: thread -> fixed channel e, queries qb + 4j (wave-uniform q
    // => wcoord/xs reads broadcast; stores coalesced 64 consecutive floats)
    const int qb = tid >> 7;
    const size_t base = ((size_t)b * N_ + (size_t)tile * 64) * H_;
#pragma unroll
    for (int j = 0; j < 16; ++j) {
        const int qq = qb + 4 * j;
        float2 xq = xs[tile * 64 + qq];
        const float* wc = &wcoord[qq * 21];
        float acc = bt;
        acc += xq.x * w1x;
        acc += xq.y * w1y;
#pragma unroll
        for (int k = 0; k < KK; ++k) {
            acc += wc[2 * k + 0] * we[2 * k + 0];
            acc += wc[2 * k + 1] * we[2 * k + 1];
        }
        out[base + (size_t)qq * H_ + e] = acc;
    }
}

extern "C" void kernel_launch(void* const* d_in, const int* in_sizes, int n_in,
                              void* d_out, int out_size, void* d_ws, size_t ws_size,
                              hipStream_t stream) {
    const float* x     = (const float*)d_in[0];
    const float* Wconv = (const float*)d_in[1];
    const float* bconv = (const float*)d_in[2];
    const float* W1    = (const float*)d_in[3];
    const float* b1    = (const float*)d_in[4];
    const float* W2    = (const float*)d_in[5];
    const float* b2    = (const float*)d_in[6];
    float* out  = (float*)d_out;
    float* weff = (float*)d_ws;                 // 2560 floats
    float* btot = weff + H_ * KK * 2;           // 128 floats

    precompute_kernel<<<dim3((H_ * KK * 2 + H_ + 255) / 256), dim3(256), 0, stream>>>(
        Wconv, bconv, b1, W2, b2, weff, btot);

    knn_conv_kernel<<<dim3(B_ * (N_ / 64)), dim3(512), 0, stream>>>(
        x, W1, weff, btot, out);
}

// Round 6
// 201.167 us; speedup vs baseline: 2.4007x; 1.1158x over previous
//
#include <hip/hip_runtime.h>
#include <cfloat>
#include <stdint.h>

#define B_   16
#define N_   2048
#define KK   10          // window = K+1
#define H_   128
#define NW   8           // waves per block
#define CPW  (N_ / NW)   // 256 candidates per wave
#define SUB  32          // sub-chunk size for skip tests
#define NSUB (CPW / SUB) // 8

// ---- precompute fused weights: Weff[e][k][c] = sum_h W2[e,h]*Wconv[h,c,k]
__global__ void precompute_kernel(const float* __restrict__ Wconv,
                                  const float* __restrict__ bconv,
                                  const float* __restrict__ b1,
                                  const float* __restrict__ W2,
                                  const float* __restrict__ b2,
                                  float* __restrict__ weff,   // [H_*20]
                                  float* __restrict__ btot)   // [H_]
{
    int gid = blockIdx.x * blockDim.x + threadIdx.x;
    if (gid < H_ * KK * 2) {
        int e = gid / 20, r = gid % 20, k = r >> 1, c = r & 1;
        float acc = 0.f;
        for (int h = 0; h < H_; ++h)
            acc += W2[e * H_ + h] * Wconv[h * (2 * KK) + c * KK + k];
        weff[gid] = acc;
    } else if (gid < H_ * KK * 2 + H_) {
        int e = gid - H_ * KK * 2;
        float acc = b1[e] + b2[e];
        for (int h = 0; h < H_; ++h)
            acc += W2[e * H_ + h] * bconv[h];
        btot[e] = acc;
    }
}

__device__ inline uint32_t f32_ordered(float f) {
    uint32_t u = __float_as_uint(f);
    return (u & 0x80000000u) ? ~u : (u | 0x80000000u);
}

// ---- per-batch sort by x-coordinate (bitonic in LDS).
// xsorted[b][i] = (px, py, sm, orig_idx_bits), ascending px.
__global__ __launch_bounds__(512) void sortx_kernel(const float* __restrict__ x,
                                                    float4* __restrict__ xsorted)
{
#pragma clang fp contract(off)
    __shared__ uint64_t sk[N_];
    const int tid = threadIdx.x;
    const int b   = blockIdx.x;
    const float2* xb = (const float2*)(x + (size_t)b * N_ * 2);

    for (int i = tid; i < N_; i += 512)
        sk[i] = ((uint64_t)f32_ordered(xb[i].x) << 32) | (uint32_t)i;
    __syncthreads();

    for (int size = 2; size <= N_; size <<= 1) {
        for (int stride = size >> 1; stride > 0; stride >>= 1) {
            for (int t = tid; t < N_ / 2; t += 512) {
                int i = t + (t & ~(stride - 1));
                int j = i + stride;
                bool up = ((i & size) == 0);
                uint64_t a = sk[i], c = sk[j];
                if (up ? (a > c) : (a < c)) { sk[i] = c; sk[j] = a; }
            }
            __syncthreads();
        }
    }
    for (int i = tid; i < N_; i += 512) {
        uint32_t idx = (uint32_t)sk[i];
        float2 p = xb[idx];
        float sm = p.x * p.x + p.y * p.y;      // no FMA (matches np sum order)
        xsorted[(size_t)b * N_ + i] = make_float4(p.x, p.y, sm, __uint_as_float(idx));
    }
}

// ---- main kernel: 512 threads = 8 waves per 64 sorted queries.
// wave w scans sorted slice [w*256,(w+1)*256) with x-gap pruning.
__global__ __launch_bounds__(512, 4) void knn_conv_kernel(
    const float4* __restrict__ xsorted,  // [B][N] sorted by x
    const float* __restrict__ W1,
    const float* __restrict__ weff,
    const float* __restrict__ btot,
    float* __restrict__ out)             // [B][N][H] (original row order)
{
#pragma clang fp contract(off)
    __shared__ float4   xs4[N_];          // 32 KB
    __shared__ uint64_t mkeys[64 * 81];   // 41.47 KB  [q][w*10+j], stride 81 u64
    __shared__ float    wcoord[64 * 21];  //  5.25 KB

    const int tid  = threadIdx.x;
    const int w    = tid >> 6;
    const int l    = tid & 63;
    const int b    = blockIdx.x >> 5;
    const int tile = blockIdx.x & 31;

    const float4* xb = xsorted + (size_t)b * N_;
    for (int i = tid; i < N_; i += 512) xs4[i] = xb[i];
    __syncthreads();

    const int n = tile * 64 + l;
    const float4 qv  = xs4[n];
    const float  qx = qv.x, qy = qv.y, sqn = qv.z;
    const float  qa = xs4[tile * 64].x;        // tile x-range (uniform)
    const float  qb = xs4[tile * 64 + 63].x;

    // sorted-10 of u64 keys: (d2_bits<<32) | (orig_idx<<11) | sorted_pos.
    // u64 '<' == (d2 asc, then orig idx asc) — exact stable-argsort ties.
    uint64_t hk[KK];
#pragma unroll
    for (int j = 0; j < KK; ++j) hk[j] = 0xFFFFFFFFFFFFFFFFull;

    const int  m0 = w * CPW;
    const bool fromLeft = (xs4[m0 + CPW - 1].x < qa);  // slice left of tile
    for (int cc = 0; cc < NSUB; ++cc) {
        const int ccc = fromLeft ? (NSUB - 1 - cc) : cc;  // nearest chunk first
        const int mc  = m0 + ccc * SUB;
        // conservative skip: min possible |dx| between chunk and tile
        float xa   = xs4[mc].x;
        float xbnd = xs4[mc + SUB - 1].x;
        float gap  = fmaxf(0.0f, fmaxf(qa - xbnd, xa - qb));
        // wave-max current 10th-smallest d2 (FLT_MAX while unfilled)
        uint32_t h9u = (uint32_t)(hk[KK - 1] >> 32);
        float wm = (h9u >= 0x7F800000u) ? FLT_MAX : __uint_as_float(h9u);
        wm = fmaxf(wm, __shfl_xor(wm, 1,  64));
        wm = fmaxf(wm, __shfl_xor(wm, 2,  64));
        wm = fmaxf(wm, __shfl_xor(wm, 4,  64));
        wm = fmaxf(wm, __shfl_xor(wm, 8,  64));
        wm = fmaxf(wm, __shfl_xor(wm, 16, 64));
        wm = fmaxf(wm, __shfl_xor(wm, 32, 64));
        if (__builtin_fmaf(gap, gap, -1e-4f) > wm) continue;  // margin >> f32 d2 error

        for (int mm = 0; mm < SUB; ++mm) {
            const int m = mc + mm;                 // wave-uniform -> broadcast
            float4 c4 = xs4[m];
            float s  = sqn + c4.z;
            float pr = qx * c4.x;                        // rn(qx*px)
            float dt = __builtin_fmaf(qy, c4.y, pr);     // fma accumulate (as np)
            float d2 = __builtin_fmaf(-2.0f, dt, s);     // rn(s - 2*dot)
            float dc = d2 > 0.0f ? d2 : 0.0f;
            uint32_t oi = __float_as_uint(c4.w);         // original index
            uint64_t key = ((uint64_t)__float_as_uint(dc) << 32)
                         | (oi << 11) | (uint32_t)m;
            if (key < hk[KK - 1]) {
#pragma unroll
                for (int j = KK - 1; j >= 1; --j) {
                    bool cj  = key < hk[j];
                    bool cjm = key < hk[j - 1];
                    hk[j] = cj ? (cjm ? hk[j - 1] : key) : hk[j];
                }
                hk[0] = (key < hk[0]) ? key : hk[0];
            }
        }
    }

    {
        const int mb = l * 81 + w * 10;
#pragma unroll
        for (int j = 0; j < KK; ++j) mkeys[mb + j] = hk[j];
    }

    // hoist epilogue weights (overlaps barrier latency)
    const int e = tid & 127;
    float we[20];
    {
        const float4* wp = (const float4*)(weff + e * 20);
#pragma unroll
        for (int r = 0; r < 5; ++r) {
            float4 v = wp[r];
            we[4 * r + 0] = v.x; we[4 * r + 1] = v.y;
            we[4 * r + 2] = v.z; we[4 * r + 3] = v.w;
        }
    }
    const float w1x = W1[e * 2 + 0];
    const float w1y = W1[e * 2 + 1];
    const float bt  = btot[e];
    __syncthreads();

    // merge 8 sorted u64 lists per query (keys unique: pos field disjoint)
    if (tid < 64) {
        int p0 = 0, p1 = 0, p2 = 0, p3 = 0, p4 = 0, p5 = 0, p6 = 0, p7 = 0;
        const int mb = tid * 81;
#pragma unroll
        for (int sel = 0; sel < KK; ++sel) {
            uint64_t best = 0xFFFFFFFFFFFFFFFFull;
            int bw = 0, bpos = 0;
#define SCAN(WW, PW)                                                    \
            {                                                           \
                uint64_t v = mkeys[mb + WW * 10 + PW];                  \
                bool c = v < best;                                      \
                best = c ? v : best;                                    \
                bw   = c ? WW : bw;                                     \
            }
            SCAN(0, p0) SCAN(1, p1) SCAN(2, p2) SCAN(3, p3)
            SCAN(4, p4) SCAN(5, p5) SCAN(6, p6) SCAN(7, p7)
#undef SCAN
            p0 += (bw == 0); p1 += (bw == 1); p2 += (bw == 2); p3 += (bw == 3);
            p4 += (bw == 4); p5 += (bw == 5); p6 += (bw == 6); p7 += (bw == 7);
            bpos = (int)(best & 0x7FF);
            float4 c = xs4[bpos];
            const int k = (KK - 1) - sel;      // flip: nearest -> k=9
            wcoord[tid * 21 + 2 * k + 0] = c.x;
            wcoord[tid * 21 + 2 * k + 1] = c.y;
        }
    }
    __syncthreads();

    // epilogue: thread -> channel e; rows scattered to ORIGINAL indices
    // (128 consecutive floats per row stay coalesced per wave-store).
    const int qb_ = tid >> 7;
    const size_t obase = (size_t)b * N_ * H_;
#pragma unroll
    for (int jj = 0; jj < 16; ++jj) {
        const int qq = qb_ + 4 * jj;
        float4 xq = xs4[tile * 64 + qq];
        uint32_t orig = __float_as_uint(xq.w);
        const float* wc = &wcoord[qq * 21];
        float acc = bt;
        acc += xq.x * w1x;
        acc += xq.y * w1y;
#pragma unroll
        for (int k = 0; k < KK; ++k) {
            acc += wc[2 * k + 0] * we[2 * k + 0];
            acc += wc[2 * k + 1] * we[2 * k + 1];
        }
        out[obase + (size_t)orig * H_ + e] = acc;
    }
}

extern "C" void kernel_launch(void* const* d_in, const int* in_sizes, int n_in,
                              void* d_out, int out_size, void* d_ws, size_t ws_size,
                              hipStream_t stream) {
    const float* x     = (const float*)d_in[0];
    const float* Wconv = (const float*)d_in[1];
    const float* bconv = (const float*)d_in[2];
    const float* W1    = (const float*)d_in[3];
    const float* b1    = (const float*)d_in[4];
    const float* W2    = (const float*)d_in[5];
    const float* b2    = (const float*)d_in[6];
    float* out  = (float*)d_out;
    float* weff = (float*)d_ws;                           // 2560 floats
    float* btot = weff + H_ * KK * 2;                     // 128 floats
    float4* xsorted = (float4*)((char*)d_ws + 16384);     // 16 batches * 2048 * 16B

    precompute_kernel<<<dim3((H_ * KK * 2 + H_ + 255) / 256), dim3(256), 0, stream>>>(
        Wconv, bconv, b1, W2, b2, weff, btot);
    sortx_kernel<<<dim3(B_), dim3(512), 0, stream>>>(x, xsorted);
    knn_conv_kernel<<<dim3(B_ * (N_ / 64)), dim3(512), 0, stream>>>(
        xsorted, W1, weff, btot, out);
}

// Round 7
// 161.754 us; speedup vs baseline: 2.9856x; 1.2437x over previous
//
#include <hip/hip_runtime.h>
#include <cfloat>
#include <stdint.h>

#define B_   16
#define N_   2048
#define KK   10          // window = K+1
#define H_   128
#define SUB  32          // chunk size
#define NCH  (N_ / SUB)  // 64 chunks

__device__ inline uint32_t f32_ordered(float f) {
    uint32_t u = __float_as_uint(f);
    return (u & 0x80000000u) ? ~u : (u | 0x80000000u);
}

// ---- fused setup: blocks 0..15 bitonic-sort one batch each by x;
//      blocks 16..18 precompute weff/btot.
__global__ __launch_bounds__(1024) void setup_kernel(
    const float* __restrict__ x,
    const float* __restrict__ Wconv, const float* __restrict__ bconv,
    const float* __restrict__ b1,    const float* __restrict__ W2,
    const float* __restrict__ b2,
    float4* __restrict__ xsorted,    // [B][N] (px,py,sm,orig_idx_bits)
    float*  __restrict__ weff,       // [H*20]
    float*  __restrict__ btot)       // [H]
{
#pragma clang fp contract(off)
    __shared__ uint64_t sk[N_];
    const int tid = threadIdx.x;
    if (blockIdx.x >= 16) {
        int gid = (blockIdx.x - 16) * 1024 + tid;
        if (gid < H_ * KK * 2) {
            int e = gid / 20, r = gid % 20, k = r >> 1, c = r & 1;
            float acc = 0.f;
            for (int h = 0; h < H_; ++h)
                acc += W2[e * H_ + h] * Wconv[h * (2 * KK) + c * KK + k];
            weff[gid] = acc;
        } else if (gid < H_ * KK * 2 + H_) {
            int e = gid - H_ * KK * 2;
            float acc = b1[e] + b2[e];
            for (int h = 0; h < H_; ++h) acc += W2[e * H_ + h] * bconv[h];
            btot[e] = acc;
        }
        return;
    }
    const int b = blockIdx.x;
    const float2* xb = (const float2*)(x + (size_t)b * N_ * 2);
    for (int i = tid; i < N_; i += 1024)
        sk[i] = ((uint64_t)f32_ordered(xb[i].x) << 32) | (uint32_t)i;
    __syncthreads();
    for (int size = 2; size <= N_; size <<= 1) {
        for (int stride = size >> 1; stride > 0; stride >>= 1) {
            int i = 2 * tid - (tid & (stride - 1));   // 1024 threads = 1024 CEs
            int j = i + stride;
            bool up = ((i & size) == 0);
            uint64_t a = sk[i], c = sk[j];
            if (up ? (a > c) : (a < c)) { sk[i] = c; sk[j] = a; }
            __syncthreads();
        }
    }
    for (int i = tid; i < N_; i += 1024) {
        uint32_t idx = (uint32_t)sk[i];
        float2 p = xb[idx];
        float sm = p.x * p.x + p.y * p.y;      // no FMA (np sum convention)
        xsorted[(size_t)b * N_ + i] = make_float4(p.x, p.y, sm, __uint_as_float(idx));
    }
}

// ---- main kernel: 512 threads = 8 waves per 64 sorted queries.
// wave w owns chunks c == w (mod 8); phase1 = nearest owned chunk
// (the 8 waves' nearest chunks tile the tile's neighborhood), phase2 =
// outward two-pointer expansion with conservative x-gap termination.
__global__ __launch_bounds__(512, 4) void knn_conv_kernel(
    const float4* __restrict__ xsorted,
    const float* __restrict__ W1,
    const float* __restrict__ weff,
    const float* __restrict__ btot,
    float* __restrict__ out)
{
#pragma clang fp contract(off)
    __shared__ float4   xs4[N_];          // 32 KB
    __shared__ uint64_t mkeys[64 * 81];   // 40.5 KB
    __shared__ float    wcoord[64 * 21];  //  5.25 KB

    const int tid  = threadIdx.x;
    const int w    = tid >> 6;
    const int l    = tid & 63;
    const int b    = blockIdx.x >> 5;
    const int tile = blockIdx.x & 31;

    const float4* xb = xsorted + (size_t)b * N_;
    for (int i = tid; i < N_; i += 512) xs4[i] = xb[i];
    __syncthreads();

    const int    n  = tile * 64 + l;
    const float4 qv = xs4[n];
    const float  qx = qv.x, qy = qv.y, sqn = qv.z;
    const float  qa  = xs4[tile * 64].x;       // tile x-range (uniform)
    const float  qbx = xs4[tile * 64 + 63].x;

    // sorted-10 of u64 keys: (d2_bits<<32)|(orig_idx<<11)|sorted_pos.
    const uint64_t KINIT = (((uint64_t)0x7F7FFFFFu) << 32) | 0x3FFFFFu; // FLT_MAX d2
    uint64_t hk[KK];
#pragma unroll
    for (int j = 0; j < KK; ++j) hk[j] = KINIT;
    float h9d = FLT_MAX;   // d2 field of hk[9] as float (cheap guard)

    auto scan_chunk = [&](int mc) {
        for (int mm = 0; mm < SUB; ++mm) {
            const int m = mc + mm;               // wave-uniform -> broadcast
            float4 c4 = xs4[m];
            float s  = sqn + c4.z;
            float pr = qx * c4.x;                        // rn(qx*px)
            float dt = __builtin_fmaf(qy, c4.y, pr);     // fma accumulate (np)
            float d2 = __builtin_fmaf(-2.0f, dt, s);     // rn(s - 2*dot)
            float dc = d2 > 0.0f ? d2 : 0.0f;
            if (dc <= h9d) {                     // <= so exact ties enter
                uint32_t oi = __float_as_uint(c4.w);
                uint64_t key = ((uint64_t)__float_as_uint(dc) << 32)
                             | (oi << 11) | (uint32_t)m;
                if (key < hk[KK - 1]) {
#pragma unroll
                    for (int j = KK - 1; j >= 1; --j) {
                        bool cj  = key < hk[j];
                        bool cjm = key < hk[j - 1];
                        hk[j] = cj ? (cjm ? hk[j - 1] : key) : hk[j];
                    }
                    hk[0] = (key < hk[0]) ? key : hk[0];
                }
                h9d = __uint_as_float((uint32_t)(hk[KK - 1] >> 32));
            }
        }
    };

    // phase 1: nearest owned chunk (unconditional; seeds a tight bound)
    const int ct2 = 2 * tile;
    const int a   = (w - ct2) & 7;
    const int c1  = ct2 + a;
    const int c2  = c1 - 8;
    int c_near = (a <= 4) ? c1 : c2;
    if (c1 > NCH - 1) c_near = c2;
    if (c2 < 0)       c_near = c1;
    scan_chunk(c_near * SUB);

    // phase 2: two-pointer outward expansion; gaps monotone per side, so a
    // failed skip test kills that side for good. Control flow wave-uniform.
    int  cl = c_near - 8, cr = c_near + 8;
    bool la = (cl >= 0), ra = (cr <= NCH - 1);
    while (la || ra) {
        float wm = h9d;                       // wave-max of 10th-best d2
        wm = fmaxf(wm, __shfl_xor(wm, 1,  64));
        wm = fmaxf(wm, __shfl_xor(wm, 2,  64));
        wm = fmaxf(wm, __shfl_xor(wm, 4,  64));
        wm = fmaxf(wm, __shfl_xor(wm, 8,  64));
        wm = fmaxf(wm, __shfl_xor(wm, 16, 64));
        wm = fmaxf(wm, __shfl_xor(wm, 32, 64));
        float gl = la ? (qa - xs4[cl * SUB + SUB - 1].x) : FLT_MAX;  // >= 0
        float gr = ra ? (xs4[cr * SUB].x - qbx)          : FLT_MAX;  // >= 0
        bool pickL = la && (!ra || gl <= gr);
        if (pickL) {
            if (__builtin_fmaf(gl, gl, -4e-6f) > wm) la = false;  // margin >> f32 d2 err
            else { scan_chunk(cl * SUB); cl -= 8; la = (cl >= 0); }
        } else {
            if (__builtin_fmaf(gr, gr, -4e-6f) > wm) ra = false;
            else { scan_chunk(cr * SUB); cr += 8; ra = (cr <= NCH - 1); }
        }
    }

    // publish partial lists
    {
        const int mb = l * 81 + w * 10;
#pragma unroll
        for (int j = 0; j < KK; ++j) mkeys[mb + j] = hk[j];
    }

    // hoist epilogue weights (latency overlaps the barrier)
    const int e = tid & 127;
    float we[20];
    {
        const float4* wp = (const float4*)(weff + e * 20);
#pragma unroll
        for (int r = 0; r < 5; ++r) {
            float4 v = wp[r];
            we[4 * r + 0] = v.x; we[4 * r + 1] = v.y;
            we[4 * r + 2] = v.z; we[4 * r + 3] = v.w;
        }
    }
    const float w1x = W1[e * 2 + 0];
    const float w1y = W1[e * 2 + 1];
    const float bt  = btot[e];
    __syncthreads();

    // parallel merge: 8 lanes per query (q = tid>>3, r = tid&7), groups of 8
    // aligned within a wave -> shfl_xor masks 1/2/4 stay in-group. Keys are
    // unique (pos field), so exactly one winner per selection.
    {
        const int q = tid >> 3;
        const int r = tid & 7;
        const int mb = q * 81 + r * 10;
        int p = 0;
#pragma unroll
        for (int sel = 0; sel < KK; ++sel) {
            uint64_t v = (p < KK) ? mkeys[mb + p] : 0xFFFFFFFFFFFFFFFFull;
            uint64_t t1 = __shfl_xor((unsigned long long)v, 1, 64);
            uint64_t m1 = v  < t1 ? v  : t1;
            uint64_t t2 = __shfl_xor((unsigned long long)m1, 2, 64);
            uint64_t m2 = m1 < t2 ? m1 : t2;
            uint64_t t4 = __shfl_xor((unsigned long long)m2, 4, 64);
            uint64_t vm = m2 < t4 ? m2 : t4;
            if (v == vm) {
                ++p;
                float4 c = xs4[(int)(vm & 0x7FF)];
                const int k = (KK - 1) - sel;          // flip: nearest -> k=9
                wcoord[q * 21 + 2 * k + 0] = c.x;
                wcoord[q * 21 + 2 * k + 1] = c.y;
            }
        }
    }
    __syncthreads();

    // epilogue: thread -> channel e; rows scattered to ORIGINAL indices
    // (128 consecutive floats per row, coalesced per wave-store).
    const int qb_ = tid >> 7;
    const size_t obase = (size_t)b * N_ * H_;
#pragma unroll
    for (int jj = 0; jj < 16; ++jj) {
        const int qq = qb_ + 4 * jj;
        float4 xq = xs4[tile * 64 + qq];
        uint32_t orig = __float_as_uint(xq.w);
        const float* wc = &wcoord[qq * 21];
        float acc = bt;
        acc += xq.x * w1x;
        acc += xq.y * w1y;
#pragma unroll
        for (int k = 0; k < KK; ++k) {
            acc += wc[2 * k + 0] * we[2 * k + 0];
            acc += wc[2 * k + 1] * we[2 * k + 1];
        }
        out[obase + (size_t)orig * H_ + e] = acc;
    }
}

extern "C" void kernel_launch(void* const* d_in, const int* in_sizes, int n_in,
                              void* d_out, int out_size, void* d_ws, size_t ws_size,
                              hipStream_t stream) {
    const float* x     = (const float*)d_in[0];
    const float* Wconv = (const float*)d_in[1];
    const float* bconv = (const float*)d_in[2];
    const float* W1    = (const float*)d_in[3];
    const float* b1    = (const float*)d_in[4];
    const float* W2    = (const float*)d_in[5];
    const float* b2    = (const float*)d_in[6];
    float* out  = (float*)d_out;
    float* weff = (float*)d_ws;                           // 2560 floats
    float* btot = weff + H_ * KK * 2;                     // 128 floats
    float4* xsorted = (float4*)((char*)d_ws + 16384);     // 16*2048*16B

    setup_kernel<<<dim3(19), dim3(1024), 0, stream>>>(
        x, Wconv, bconv, b1, W2, b2, xsorted, weff, btot);
    knn_conv_kernel<<<dim3(B_ * (N_ / 64)), dim3(512), 0, stream>>>(
        xsorted, W1, weff, btot, out);
}